// Round 9
// baseline (238.269 us; speedup 1.0000x reference)
//
#include <hip/hip_runtime.h>
#include <hip/hip_bf16.h>
#include <stdint.h>

typedef _Float16 f16;
typedef _Float16 f16x8 __attribute__((ext_vector_type(8)));
typedef float f32x4 __attribute__((ext_vector_type(4)));

#define AS1 __attribute__((address_space(1)))
#define AS3 __attribute__((address_space(3)))

// ---------------------------------------------------------------------------
// Transpose + fp32->fp16 convert:  src [R][C] f32  ->  dst [C][R] f16
// (used only for Wqkv and Wout now)
// ---------------------------------------------------------------------------
__global__ __launch_bounds__(256) void tr_cvt_kernel(
    const float* __restrict__ src, f16* __restrict__ dst, int R, int C)
{
    __shared__ float tile[64][65];
    const int b = blockIdx.z;
    src += (size_t)b * R * C;
    dst += (size_t)b * R * C;
    const int c0 = blockIdx.x * 64;
    const int r0 = blockIdx.y * 64;
    const int t = threadIdx.x;
    {
        const int cc = (t & 15) * 4;
        const int rr = t >> 4;
#pragma unroll
        for (int p = 0; p < 4; ++p) {
            const int r = rr + p * 16;
            const float4 v = *(const float4*)(src + (size_t)(r0 + r) * C + c0 + cc);
            tile[r][cc + 0] = v.x; tile[r][cc + 1] = v.y;
            tile[r][cc + 2] = v.z; tile[r][cc + 3] = v.w;
        }
    }
    __syncthreads();
    {
        const int rq = (t & 15) * 4;
        const int cp = t >> 4;
#pragma unroll
        for (int p = 0; p < 4; ++p) {
            const int c = cp + p * 16;
            ushort4 o;
            f16 h0 = (f16)tile[rq + 0][c];
            f16 h1 = (f16)tile[rq + 1][c];
            f16 h2 = (f16)tile[rq + 2][c];
            f16 h3 = (f16)tile[rq + 3][c];
            o.x = __builtin_bit_cast(unsigned short, h0);
            o.y = __builtin_bit_cast(unsigned short, h1);
            o.z = __builtin_bit_cast(unsigned short, h2);
            o.w = __builtin_bit_cast(unsigned short, h3);
            *(ushort4*)(dst + (size_t)(c0 + c) * R + r0 + rq) = o;
        }
    }
}

// ===========================================================================
// syk: fused transpose+convert GEMM. Source x[k][m] f32 (k = sequence axis).
// Reg-staging (T14): issue f32 loads of tile t+1 early; ds_read+MFMA tile t;
// then cvt->f16 + swizzled ds_write; lgkmcnt(0); single barrier per step.
// LDS logical [m][64 k] f16; phys 16B-chunk = logical ^ ((m>>2)&7):
//   writes conflict-free (c = w ^ (lane&7) spans 8 groups), reads 2-way (free).
// ===========================================================================
__device__ __forceinline__ void load_f32(
    const float* __restrict__ Ag, const float* __restrict__ Bg,
    int kb, int w, int lane, float4 (&a4)[8], float4 (&b4)[8])
{
#pragma unroll
    for (int p = 0; p < 8; ++p)
        a4[p] = *(const float4*)(Ag + (size_t)(kb + w * 8 + p) * 1024 + lane * 4);
#pragma unroll
    for (int p = 0; p < 8; ++p)
        b4[p] = *(const float4*)(Bg + (size_t)(kb + w * 8 + p) * 1024 + lane * 4);
}

__device__ __forceinline__ void write_f16(
    f16* Aw, f16* Bw, int w, int lane,
    const float4 (&a4)[8], const float4 (&b4)[8])
{
    const int c = w ^ (lane & 7);
#pragma unroll
    for (int i = 0; i < 4; ++i) {
        f16x8 ha, hb;
#pragma unroll
        for (int p = 0; p < 8; ++p) {
            const float4 va = a4[p];
            const float4 vb = b4[p];
            ha[p] = (f16)((i == 0) ? va.x : (i == 1) ? va.y : (i == 2) ? va.z : va.w);
            hb[p] = (f16)((i == 0) ? vb.x : (i == 1) ? vb.y : (i == 2) ? vb.z : vb.w);
        }
        *(f16x8*)&Aw[(lane * 4 + i) * 64 + c * 8] = ha;
        *(f16x8*)&Bw[(lane * 4 + i) * 64 + c * 8] = hb;
    }
}

// K1: Gp[s][b] = (f16(x_b))^T slice self-product, split-K=2, K=2048/block.
// grid: 256 blocks (16 tiles x 8 batch x 2 splits), XCD-chunked swizzle.
__global__ __launch_bounds__(512, 2) void gemm_syk256(
    const float* __restrict__ x, f16* __restrict__ Gp)
{
    __shared__ f16 As[2 * 256 * 64];   // [buf][m 256][k 64]
    __shared__ f16 Bs[2 * 256 * 64];
    const int orig = blockIdx.x;
    const int l = (orig & 7) * 32 + (orig >> 3);   // 256 = 8*32, bijective
    const int tile = l & 15, b = (l >> 4) & 7, s = l >> 7;
    const int ti = tile >> 2, tj = tile & 3;

    const float* base = x + (size_t)b * (4096 * 1024) + (size_t)s * 2048 * 1024;
    const float* Ag = base + ti * 256;
    const float* Bg = base + tj * 256;

    const int tid = threadIdx.x;
    const int lane = tid & 63, w = tid >> 6;
    const int wr = w >> 2, wc = w & 3;
    const int cl = lane & 15, kg = lane >> 4;

    f32x4 acc[8][4];
#pragma unroll
    for (int i = 0; i < 8; ++i)
#pragma unroll
        for (int j = 0; j < 4; ++j) acc[i][j] = f32x4{0.f, 0.f, 0.f, 0.f};

    // prologue: stage tile 0
    {
        float4 a4[8], b4[8];
        load_f32(Ag, Bg, 0, w, lane, a4, b4);
        write_f16(As, Bs, w, lane, a4, b4);
        asm volatile("s_waitcnt lgkmcnt(0)" ::: "memory");
        __builtin_amdgcn_s_barrier();
    }

#pragma unroll 1
    for (int t = 0; t < 32; ++t) {
        const int cur = t & 1;
        float4 a4[8], b4[8];
        if (t + 1 < 32)
            load_f32(Ag, Bg, (t + 1) * 64, w, lane, a4, b4);   // issue early

        const f16* Ab = As + cur * 16384;
        const f16* Bb = Bs + cur * 16384;
#pragma unroll
        for (int kk = 0; kk < 2; ++kk) {
            f16x8 af[8], bf[4];
#pragma unroll
            for (int i = 0; i < 8; ++i) {
                const int m = wr * 128 + i * 16 + cl;
                const int c = (kk * 4 + kg) ^ ((m >> 2) & 7);
                af[i] = *(const f16x8*)&Ab[m * 64 + c * 8];
            }
#pragma unroll
            for (int j = 0; j < 4; ++j) {
                const int m = wc * 64 + j * 16 + cl;
                const int c = (kk * 4 + kg) ^ ((m >> 2) & 7);
                bf[j] = *(const f16x8*)&Bb[m * 64 + c * 8];
            }
            __builtin_amdgcn_s_setprio(1);
#pragma unroll
            for (int i = 0; i < 8; ++i)
#pragma unroll
                for (int j = 0; j < 4; ++j)
                    acc[i][j] = __builtin_amdgcn_mfma_f32_16x16x32_f16(af[i], bf[j], acc[i][j], 0, 0, 0);
            __builtin_amdgcn_s_setprio(0);
        }
        if (t + 1 < 32)
            write_f16(As + (cur ^ 1) * 16384, Bs + (cur ^ 1) * 16384,
                      w, lane, a4, b4);                        // write late
        asm volatile("s_waitcnt lgkmcnt(0)" ::: "memory");
        __builtin_amdgcn_s_barrier();
    }

    f16* out = Gp + ((size_t)s * 8 + b) * 1048576;
    const int rg = lane >> 4;
#pragma unroll
    for (int i = 0; i < 8; ++i)
#pragma unroll
        for (int j = 0; j < 4; ++j)
#pragma unroll
            for (int q = 0; q < 4; ++q) {
                const int row = ti * 256 + wr * 128 + i * 16 + rg * 4 + q;
                const int col = tj * 256 + wc * 64 + j * 16 + cl;
                out[(size_t)row * 1024 + col] = (f16)acc[i][j][q];
            }
}

// ---------------------------------------------------------------------------
// reduce: G = Gp[0] + Gp[1]  (elementwise, f32 accumulate)
// ---------------------------------------------------------------------------
__global__ __launch_bounds__(256) void reduce_sum(
    const f16* __restrict__ Gp, f16* __restrict__ G)
{
    const size_t i = ((size_t)blockIdx.x * 256 + threadIdx.x) * 8;
    const f16x8 a = *(const f16x8*)(Gp + i);
    const f16x8 c = *(const f16x8*)(Gp + 8388608 + i);
    f16x8 o;
#pragma unroll
    for (int j = 0; j < 8; ++j) o[j] = (f16)((float)a[j] + (float)c[j]);
    *(f16x8*)(G + i) = o;
}

// ===========================================================================
// r5-exact 256^2 core (counted vmcnt(8), two barriers) — used by qv.
// ===========================================================================
__device__ __forceinline__ void stage256(
    const f16* __restrict__ src, int ld, char* ldsbase, int tid)
{
    const int lane = tid & 63;
    const int gch = ((lane & 7) ^ (lane >> 3)) * 8;   // inverse-swizzled source
    const int rowl = tid >> 3;
    const int wbase = (tid >> 3) & ~7;                // wave-uniform
#pragma unroll
    for (int p = 0; p < 4; ++p) {
        const f16* s = src + (size_t)(p * 64 + rowl) * ld + gch;
        __builtin_amdgcn_global_load_lds(
            (const AS1 uint32_t*)s,
            (AS3 uint32_t*)(ldsbase + (p * 64 + wbase) * 128), 16, 0, 0);
    }
}

__device__ __forceinline__ void gemm256_core(
    const f16* __restrict__ A, const f16* __restrict__ Bt,
    int lda, int ldb, int nsteps,
    f16* As, f16* Bs, f32x4 (&acc)[8][4], int tid)
{
    const int lane = tid & 63, w = tid >> 6;
    const int wr = w >> 2, wc = w & 3;
    const int cl = lane & 15, kg = lane >> 4, b7 = lane & 7;

    stage256(A, lda, (char*)As, tid);
    stage256(Bt, ldb, (char*)Bs, tid);

#pragma unroll 1
    for (int t = 0; t < nsteps; ++t) {
        const int cur = t & 1;
        if (t + 1 < nsteps) {
            const int k0 = (t + 1) * 64;
            stage256(A + k0, lda, (char*)As + (cur ^ 1) * 32768, tid);
            stage256(Bt + k0, ldb, (char*)Bs + (cur ^ 1) * 32768, tid);
            asm volatile("s_waitcnt vmcnt(8)" ::: "memory");
        } else {
            asm volatile("s_waitcnt vmcnt(0)" ::: "memory");
        }
        __builtin_amdgcn_s_barrier();
        const f16* Ab = As + cur * 16384;
        const f16* Bb = Bs + cur * 16384;
#pragma unroll
        for (int kk = 0; kk < 2; ++kk) {
            const int ch = (kk * 4 + kg) ^ b7;
            f16x8 af[8], bf[4];
#pragma unroll
            for (int i = 0; i < 8; ++i)
                af[i] = *(const f16x8*)&Ab[(wr * 128 + i * 16 + cl) * 64 + ch * 8];
#pragma unroll
            for (int j = 0; j < 4; ++j)
                bf[j] = *(const f16x8*)&Bb[(wc * 64 + j * 16 + cl) * 64 + ch * 8];
#pragma unroll
            for (int i = 0; i < 8; ++i)
#pragma unroll
                for (int j = 0; j < 4; ++j)
                    acc[i][j] = __builtin_amdgcn_mfma_f32_16x16x32_f16(af[i], bf[j], acc[i][j], 0, 0, 0);
        }
        __builtin_amdgcn_s_barrier();
    }
}

// K2 fused (256^2): UW2[b] = [Wq^T G_b ; Wv^T G_b], K=1024.
__global__ __launch_bounds__(512, 2) void gemm_qv256(
    const f16* __restrict__ WqkvT, const f16* __restrict__ G,
    f16* __restrict__ UW2)
{
    __shared__ f16 As[2 * 256 * 64];
    __shared__ f16 Bs[2 * 256 * 64];
    const int orig = blockIdx.x;
    const int l = (orig & 7) * 32 + (orig >> 3);
    const int bx = l & 3, by = (l >> 2) & 7, b = l >> 5;
    const int arow = (by < 4) ? by * 256 : 2048 + (by - 4) * 256;  // skip Wk

    const f16* A  = WqkvT + (size_t)arow * 1024;
    const f16* Bt = G + (size_t)b * 1048576 + (size_t)bx * 256 * 1024;

    f32x4 acc[8][4];
#pragma unroll
    for (int i = 0; i < 8; ++i)
#pragma unroll
        for (int j = 0; j < 4; ++j) acc[i][j] = f32x4{0.f, 0.f, 0.f, 0.f};

    gemm256_core(A, Bt, 1024, 1024, 16, As, Bs, acc, threadIdx.x);

    f16* C = UW2 + (size_t)b * 2097152;
    const int lane = threadIdx.x & 63, w = threadIdx.x >> 6;
    const int wr = w >> 2, wc = w & 3;
    const int cl = lane & 15, rg = lane >> 4;
#pragma unroll
    for (int i = 0; i < 8; ++i)
#pragma unroll
        for (int j = 0; j < 4; ++j) {
            const int cc = bx * 256 + wc * 64 + j * 16 + cl;
#pragma unroll
            for (int q = 0; q < 4; ++q) {
                const int rr = by * 256 + wr * 128 + i * 16 + rg * 4 + q;
                C[(size_t)rr * 1024 + cc] = (f16)acc[i][j][q];
            }
        }
}

// ---------------------------------------------------------------------------
// Legacy 128x128 body (used by gemm_out only)
// ---------------------------------------------------------------------------
__device__ __forceinline__ void gemm_body(
    const f16* __restrict__ A, const f16* __restrict__ Bt,
    int lda, int ldb, int K, f16* As, f16* Bs,
    f32x4 (&acc)[4][4], int tid)
{
    const int lane = tid & 63, w = tid >> 6;
    const int wr = w >> 1, wc = w & 1;
    const int lrow = lane >> 3;
    const int lcol = (lane & 7) * 8;
    for (int k0 = 0; k0 < K; k0 += 64) {
#pragma unroll
        for (int p = 0; p < 4; ++p) {
            const f16* sa = A + (size_t)(p * 32 + w * 8 + lrow) * lda + k0 + lcol;
            __builtin_amdgcn_global_load_lds(
                (const AS1 uint32_t*)sa,
                (AS3 uint32_t*)((char*)As + p * 4096 + w * 1024), 16, 0, 0);
            const f16* sb = Bt + (size_t)(p * 32 + w * 8 + lrow) * ldb + k0 + lcol;
            __builtin_amdgcn_global_load_lds(
                (const AS1 uint32_t*)sb,
                (AS3 uint32_t*)((char*)Bs + p * 4096 + w * 1024), 16, 0, 0);
        }
        __syncthreads();
#pragma unroll
        for (int kk = 0; kk < 2; ++kk) {
            f16x8 af[4], bfr[4];
#pragma unroll
            for (int i = 0; i < 4; ++i)
                af[i] = *(const f16x8*)&As[(wr * 64 + i * 16 + (lane & 15)) * 64 + kk * 32 + (lane >> 4) * 8];
#pragma unroll
            for (int j = 0; j < 4; ++j)
                bfr[j] = *(const f16x8*)&Bs[(wc * 64 + j * 16 + (lane & 15)) * 64 + kk * 32 + (lane >> 4) * 8];
#pragma unroll
            for (int i = 0; i < 4; ++i)
#pragma unroll
                for (int j = 0; j < 4; ++j)
                    acc[i][j] = __builtin_amdgcn_mfma_f32_16x16x32_f16(af[i], bfr[j], acc[i][j], 0, 0, 0);
        }
        __syncthreads();
    }
}

// K4: d_out = O @ WoutT^T + bias. grid (8,4), block 256. K=1024.
__global__ __launch_bounds__(256) void gemm_out(
    const f16* __restrict__ A, const f16* __restrict__ Bt,
    const float* __restrict__ bias, float* __restrict__ Cout)
{
    __shared__ f16 As[128 * 64];
    __shared__ f16 Bs[128 * 64];
    const int tn0 = blockIdx.x * 128;
    const int tm0 = blockIdx.y * 128;
    f32x4 acc[4][4];
#pragma unroll
    for (int i = 0; i < 4; ++i)
#pragma unroll
        for (int j = 0; j < 4; ++j) acc[i][j] = f32x4{0.f, 0.f, 0.f, 0.f};

    gemm_body(A + (size_t)tm0 * 1024, Bt + (size_t)tn0 * 1024,
              1024, 1024, 1024, As, Bs, acc, threadIdx.x);

    const int lane = threadIdx.x & 63, w = threadIdx.x >> 6;
    const int wr = w >> 1, wc = w & 1;
    const int cl = lane & 15, rg = lane >> 4;
#pragma unroll
    for (int i = 0; i < 4; ++i)
#pragma unroll
        for (int j = 0; j < 4; ++j) {
            const int cc = tn0 + wc * 64 + j * 16 + cl;
            const float bv = bias[cc];
#pragma unroll
            for (int q = 0; q < 4; ++q) {
                const int rr = tm0 + wr * 64 + i * 16 + rg * 4 + q;
                Cout[(size_t)rr * 1024 + cc] = acc[i][j][q] + bv;
            }
        }
}

// ---------------------------------------------------------------------------
// Per (b,h): dots = U_h * Wk_h^T, vv = W2_h * Wv2_h^T  (64x64, K=1024),
// softmax(dots*0.125), out = attn @ vv -> O (f16)
// grid: (16 heads, 8 batches), block 512 (8 waves)
// ---------------------------------------------------------------------------
__global__ __launch_bounds__(512) void attn_small(
    const f16* __restrict__ UW2, const f16* __restrict__ WqkvT,
    f16* __restrict__ O)
{
    __shared__ float dots[64][66];
    __shared__ float vv[64][66];
    const int h = blockIdx.x, b = blockIdx.y;
    const int tid = threadIdx.x, lane = tid & 63, w = tid >> 6;
    const int isVV = w >> 2;
    const int kq = w & 3;

    const f16* Arows = UW2 + (size_t)b * (2048 * 1024)
                           + (size_t)isVV * (1024 * 1024) + (size_t)h * 64 * 1024;
    const f16* Brows = WqkvT + (size_t)(isVV ? 3072 : 1024) * 1024 + (size_t)h * 64 * 1024;

    f32x4 acc[4][4];
#pragma unroll
    for (int i = 0; i < 4; ++i)
#pragma unroll
        for (int j = 0; j < 4; ++j) acc[i][j] = f32x4{0.f, 0.f, 0.f, 0.f};

    const int cl = lane & 15, kg = lane >> 4;
    for (int ks = 0; ks < 8; ++ks) {
        const int k0 = kq * 256 + ks * 32 + kg * 8;
        f16x8 af[4], bfr[4];
#pragma unroll
        for (int i = 0; i < 4; ++i)
            af[i] = *(const f16x8*)(Arows + (size_t)(i * 16 + cl) * 1024 + k0);
#pragma unroll
        for (int j = 0; j < 4; ++j)
            bfr[j] = *(const f16x8*)(Brows + (size_t)(j * 16 + cl) * 1024 + k0);
#pragma unroll
        for (int i = 0; i < 4; ++i)
#pragma unroll
            for (int j = 0; j < 4; ++j)
                acc[i][j] = __builtin_amdgcn_mfma_f32_16x16x32_f16(af[i], bfr[j], acc[i][j], 0, 0, 0);
    }

    float (*dst)[66] = isVV ? vv : dots;
#pragma unroll
    for (int r = 0; r < 4; ++r) {
        if (kq == r) {
            if (r == 0) {
#pragma unroll
                for (int i = 0; i < 4; ++i)
#pragma unroll
                    for (int j = 0; j < 4; ++j)
#pragma unroll
                        for (int q = 0; q < 4; ++q)
                            dst[i * 16 + kg * 4 + q][j * 16 + cl] = acc[i][j][q];
            } else {
#pragma unroll
                for (int i = 0; i < 4; ++i)
#pragma unroll
                    for (int j = 0; j < 4; ++j)
#pragma unroll
                        for (int q = 0; q < 4; ++q)
                            dst[i * 16 + kg * 4 + q][j * 16 + cl] += acc[i][j][q];
            }
        }
        __syncthreads();
    }

    if (tid < 64) {
        const int r = tid;
        float mx = -1e30f;
        for (int e = 0; e < 64; ++e) {
            const float v = dots[r][e] * 0.125f;
            dots[r][e] = v;
            mx = fmaxf(mx, v);
        }
        float s = 0.f;
        for (int e = 0; e < 64; ++e) {
            const float v = __expf(dots[r][e] - mx);
            dots[r][e] = v;
            s += v;
        }
        const float inv = 1.f / s;
        for (int e = 0; e < 64; ++e) dots[r][e] *= inv;
    }
    __syncthreads();

    {
        const int r = tid >> 3, f0 = (tid & 7) * 8;
        float o[8];
#pragma unroll
        for (int i = 0; i < 8; ++i) o[i] = 0.f;
        for (int e = 0; e < 64; ++e) {
            const float a = dots[r][e];
#pragma unroll
            for (int i = 0; i < 8; ++i) o[i] += a * vv[e][f0 + i];
        }
        f16* Od = O + (size_t)b * 64 * 1024 + (size_t)r * 1024 + h * 64 + f0;
#pragma unroll
        for (int i = 0; i < 8; ++i) Od[i] = (f16)o[i];
    }
}

// ---------------------------------------------------------------------------
extern "C" void kernel_launch(void* const* d_in, const int* in_sizes, int n_in,
                              void* d_out, int out_size, void* d_ws, size_t ws_size,
                              hipStream_t stream)
{
    const float* x    = (const float*)d_in[0];  // [8][4096][1024]
    const float* Wqkv = (const float*)d_in[1];  // [1024][4096]
    const float* Wout = (const float*)d_in[2];  // [1024][1024]
    const float* bout = (const float*)d_in[3];  // [1024]

    char* ws = (char*)d_ws;
    f16* WqkvT = (f16*)(ws + 0);           // [4096][1024]        8388608 B
    f16* WoutT = (f16*)(ws + 8388608);     // [1024][1024]        2097152 B
    f16* G     = (f16*)(ws + 10485760);    // [8][1024][1024]    16777216 B
    f16* Gp    = (f16*)(ws + 27262976);    // [2][8][1024][1024] 33554432 B
    f16* UW2   = (f16*)(ws + 27262976);    // union w/ Gp (qv runs after reduce)
    f16* O     = (f16*)(ws + 60817408);    // [8][64][1024]       1048576 B

    tr_cvt_kernel<<<dim3(64, 16, 1), 256, 0, stream>>>(Wqkv, WqkvT, 1024, 4096);
    tr_cvt_kernel<<<dim3(16, 16, 1), 256, 0, stream>>>(Wout, WoutT, 1024, 1024);

    // K1: fused transpose+convert+GEMM from x directly (split-K=2)
    gemm_syk256<<<256, 512, 0, stream>>>(x, Gp);
    // G = Gp0 + Gp1
    reduce_sum<<<4096, 256, 0, stream>>>(Gp, G);
    // K2 fused: UW2 = [Wq^T G ; Wv^T G]
    gemm_qv256<<<256, 512, 0, stream>>>(WqkvT, G, UW2);
    // K3: per (b,h) small attention
    attn_small<<<dim3(16, 8), 512, 0, stream>>>(UW2, WqkvT, O);
    // K4: out = O @ WoutT^T + bias
    gemm_out<<<dim3(8, 4), 256, 0, stream>>>(O, WoutT, bout, (float*)d_out);
}

// Round 10
// 201.612 us; speedup vs baseline: 1.1818x; 1.1818x over previous
//
#include <hip/hip_runtime.h>
#include <hip/hip_bf16.h>
#include <stdint.h>

typedef _Float16 f16;
typedef _Float16 f16x8 __attribute__((ext_vector_type(8)));
typedef float f32x4 __attribute__((ext_vector_type(4)));

#define AS1 __attribute__((address_space(1)))
#define AS3 __attribute__((address_space(3)))

// ---------------------------------------------------------------------------
// Transpose + fp32->fp16 convert:  src [R][C] f32  ->  dst [C][R] f16
// ---------------------------------------------------------------------------
__global__ __launch_bounds__(256) void tr_cvt_kernel(
    const float* __restrict__ src, f16* __restrict__ dst, int R, int C)
{
    __shared__ float tile[64][65];
    const int b = blockIdx.z;
    src += (size_t)b * R * C;
    dst += (size_t)b * R * C;
    const int c0 = blockIdx.x * 64;
    const int r0 = blockIdx.y * 64;
    const int t = threadIdx.x;
    {
        const int cc = (t & 15) * 4;
        const int rr = t >> 4;
#pragma unroll
        for (int p = 0; p < 4; ++p) {
            const int r = rr + p * 16;
            const float4 v = *(const float4*)(src + (size_t)(r0 + r) * C + c0 + cc);
            tile[r][cc + 0] = v.x; tile[r][cc + 1] = v.y;
            tile[r][cc + 2] = v.z; tile[r][cc + 3] = v.w;
        }
    }
    __syncthreads();
    {
        const int rq = (t & 15) * 4;
        const int cp = t >> 4;
#pragma unroll
        for (int p = 0; p < 4; ++p) {
            const int c = cp + p * 16;
            ushort4 o;
            f16 h0 = (f16)tile[rq + 0][c];
            f16 h1 = (f16)tile[rq + 1][c];
            f16 h2 = (f16)tile[rq + 2][c];
            f16 h3 = (f16)tile[rq + 3][c];
            o.x = __builtin_bit_cast(unsigned short, h0);
            o.y = __builtin_bit_cast(unsigned short, h1);
            o.z = __builtin_bit_cast(unsigned short, h2);
            o.w = __builtin_bit_cast(unsigned short, h3);
            *(ushort4*)(dst + (size_t)(c0 + c) * R + r0 + rq) = o;
        }
    }
}

// ---------------------------------------------------------------------------
// r5-exact 256x256-tile, BK=64, 512-thread (8-wave, 2x4) GEMM core.
// Double-buffered LDS (2x32KB per matrix), global_load_lds-16B staging of
// step t+1 issued BEFORE the counted wait, s_waitcnt vmcnt(8) (never 0
// mid-loop), raw barriers. Chunk-XOR swizzle: linear LDS dest,
// inverse-swizzled global source chunk, read applies same XOR (rule 21).
// Measured: 74.8us / MfmaUtil 39.4% / 0 bank conflicts (round 5).
// ---------------------------------------------------------------------------
__device__ __forceinline__ void stage256(
    const f16* __restrict__ src, int ld, char* ldsbase, int tid)
{
    const int lane = tid & 63;
    const int gch = ((lane & 7) ^ (lane >> 3)) * 8;   // inverse-swizzled source
    const int rowl = tid >> 3;                        // 0..63 (w*8 + lane>>3)
    const int wbase = (tid >> 3) & ~7;                // wave-uniform: w*8
#pragma unroll
    for (int p = 0; p < 4; ++p) {
        const f16* s = src + (size_t)(p * 64 + rowl) * ld + gch;
        __builtin_amdgcn_global_load_lds(
            (const AS1 uint32_t*)s,
            (AS3 uint32_t*)(ldsbase + (p * 64 + wbase) * 128), 16, 0, 0);
    }
}

__device__ __forceinline__ void gemm256_core(
    const f16* __restrict__ A, const f16* __restrict__ Bt,
    int lda, int ldb, int nsteps,
    f16* As, f16* Bs, f32x4 (&acc)[8][4], int tid)
{
    const int lane = tid & 63, w = tid >> 6;
    const int wr = w >> 2, wc = w & 3;
    const int cl = lane & 15, kg = lane >> 4, b7 = lane & 7;

    // prologue: stage step 0 into buffer 0
    stage256(A, lda, (char*)As, tid);
    stage256(Bt, ldb, (char*)Bs, tid);

#pragma unroll 1
    for (int t = 0; t < nsteps; ++t) {
        const int cur = t & 1;
        if (t + 1 < nsteps) {
            const int k0 = (t + 1) * 64;
            stage256(A + k0, lda, (char*)As + (cur ^ 1) * 32768, tid);
            stage256(Bt + k0, ldb, (char*)Bs + (cur ^ 1) * 32768, tid);
            asm volatile("s_waitcnt vmcnt(8)" ::: "memory");  // step t's 8 loads done
        } else {
            asm volatile("s_waitcnt vmcnt(0)" ::: "memory");
        }
        __builtin_amdgcn_s_barrier();   // buf[cur] complete for all waves
        const f16* Ab = As + cur * 16384;
        const f16* Bb = Bs + cur * 16384;
#pragma unroll
        for (int kk = 0; kk < 2; ++kk) {
            const int ch = (kk * 4 + kg) ^ b7;   // swizzled 16B chunk
            f16x8 af[8], bf[4];
#pragma unroll
            for (int i = 0; i < 8; ++i)
                af[i] = *(const f16x8*)&Ab[(wr * 128 + i * 16 + cl) * 64 + ch * 8];
#pragma unroll
            for (int j = 0; j < 4; ++j)
                bf[j] = *(const f16x8*)&Bb[(wc * 64 + j * 16 + cl) * 64 + ch * 8];
#pragma unroll
            for (int i = 0; i < 8; ++i)
#pragma unroll
                for (int j = 0; j < 4; ++j)
                    acc[i][j] = __builtin_amdgcn_mfma_f32_16x16x32_f16(af[i], bf[j], acc[i][j], 0, 0, 0);
        }
        __builtin_amdgcn_s_barrier();   // all waves done reading buf[cur]
    }
}

// ---------------------------------------------------------------------------
// K1: Gp[s][b] = xT_b[:, s*2048 : +2048] self-product (full G, split-K=2).
// grid: 256 blocks (16 tiles x 8 batch x 2 splits), XCD-chunked swizzle.
// ---------------------------------------------------------------------------
__global__ __launch_bounds__(512, 2) void gemm_syk256(
    const f16* __restrict__ xT, f16* __restrict__ Gp)
{
    __shared__ f16 As[2 * 256 * 64];
    __shared__ f16 Bs[2 * 256 * 64];
    const int orig = blockIdx.x;
    const int l = (orig & 7) * 32 + (orig >> 3);   // 256 = 8*32, bijective
    const int tile = l & 15, b = (l >> 4) & 7, s = l >> 7;
    const int ti = tile >> 2, tj = tile & 3;

    const f16* base = xT + (size_t)b * (1024 * 4096) + (size_t)s * 2048;
    const f16* A  = base + (size_t)ti * 256 * 4096;
    const f16* Bt = base + (size_t)tj * 256 * 4096;

    f32x4 acc[8][4];
#pragma unroll
    for (int i = 0; i < 8; ++i)
#pragma unroll
        for (int j = 0; j < 4; ++j) acc[i][j] = f32x4{0.f, 0.f, 0.f, 0.f};

    gemm256_core(A, Bt, 4096, 4096, 32, As, Bs, acc, threadIdx.x);

    f16* out = Gp + ((size_t)s * 8 + b) * 1048576;
    const int lane = threadIdx.x & 63, w = threadIdx.x >> 6;
    const int wr = w >> 2, wc = w & 3;
    const int cl = lane & 15, rg = lane >> 4;
#pragma unroll
    for (int i = 0; i < 8; ++i)
#pragma unroll
        for (int j = 0; j < 4; ++j)
#pragma unroll
            for (int q = 0; q < 4; ++q) {
                const int row = ti * 256 + wr * 128 + i * 16 + rg * 4 + q;
                const int col = tj * 256 + wc * 64 + j * 16 + cl;
                out[(size_t)row * 1024 + col] = (f16)acc[i][j][q];
            }
}

// ---------------------------------------------------------------------------
// reduce: G = Gp[0] + Gp[1]  (elementwise, f32 accumulate)
// ---------------------------------------------------------------------------
__global__ __launch_bounds__(256) void reduce_sum(
    const f16* __restrict__ Gp, f16* __restrict__ G)
{
    const size_t i = ((size_t)blockIdx.x * 256 + threadIdx.x) * 8;
    const f16x8 a = *(const f16x8*)(Gp + i);
    const f16x8 c = *(const f16x8*)(Gp + 8388608 + i);
    f16x8 o;
#pragma unroll
    for (int j = 0; j < 8; ++j) o[j] = (f16)((float)a[j] + (float)c[j]);
    *(f16x8*)(G + i) = o;
}

// ---------------------------------------------------------------------------
// K2 fused (256^2): UW2[b] = [Wq^T G_b ; Wv^T G_b], K=1024.
// grid: 256 blocks (4 N x 8 M x 8 batch), XCD-chunked swizzle.
// ---------------------------------------------------------------------------
__global__ __launch_bounds__(512, 2) void gemm_qv256(
    const f16* __restrict__ WqkvT, const f16* __restrict__ G,
    f16* __restrict__ UW2)
{
    __shared__ f16 As[2 * 256 * 64];
    __shared__ f16 Bs[2 * 256 * 64];
    const int orig = blockIdx.x;
    const int l = (orig & 7) * 32 + (orig >> 3);
    const int bx = l & 3, by = (l >> 2) & 7, b = l >> 5;
    const int arow = (by < 4) ? by * 256 : 2048 + (by - 4) * 256;  // skip Wk

    const f16* A  = WqkvT + (size_t)arow * 1024;
    const f16* Bt = G + (size_t)b * 1048576 + (size_t)bx * 256 * 1024;

    f32x4 acc[8][4];
#pragma unroll
    for (int i = 0; i < 8; ++i)
#pragma unroll
        for (int j = 0; j < 4; ++j) acc[i][j] = f32x4{0.f, 0.f, 0.f, 0.f};

    gemm256_core(A, Bt, 1024, 1024, 16, As, Bs, acc, threadIdx.x);

    f16* C = UW2 + (size_t)b * 2097152;
    const int lane = threadIdx.x & 63, w = threadIdx.x >> 6;
    const int wr = w >> 2, wc = w & 3;
    const int cl = lane & 15, rg = lane >> 4;
#pragma unroll
    for (int i = 0; i < 8; ++i)
#pragma unroll
        for (int j = 0; j < 4; ++j) {
            const int cc = bx * 256 + wc * 64 + j * 16 + cl;
#pragma unroll
            for (int q = 0; q < 4; ++q) {
                const int rr = by * 256 + wr * 128 + i * 16 + rg * 4 + q;
                C[(size_t)rr * 1024 + cc] = (f16)acc[i][j][q];
            }
        }
}

// ---------------------------------------------------------------------------
// Legacy 128x128 body (used by gemm_out only)
// ---------------------------------------------------------------------------
__device__ __forceinline__ void gemm_body(
    const f16* __restrict__ A, const f16* __restrict__ Bt,
    int lda, int ldb, int K, f16* As, f16* Bs,
    f32x4 (&acc)[4][4], int tid)
{
    const int lane = tid & 63, w = tid >> 6;
    const int wr = w >> 1, wc = w & 1;
    const int lrow = lane >> 3;
    const int lcol = (lane & 7) * 8;
    for (int k0 = 0; k0 < K; k0 += 64) {
#pragma unroll
        for (int p = 0; p < 4; ++p) {
            const f16* sa = A + (size_t)(p * 32 + w * 8 + lrow) * lda + k0 + lcol;
            __builtin_amdgcn_global_load_lds(
                (const AS1 uint32_t*)sa,
                (AS3 uint32_t*)((char*)As + p * 4096 + w * 1024), 16, 0, 0);
            const f16* sb = Bt + (size_t)(p * 32 + w * 8 + lrow) * ldb + k0 + lcol;
            __builtin_amdgcn_global_load_lds(
                (const AS1 uint32_t*)sb,
                (AS3 uint32_t*)((char*)Bs + p * 4096 + w * 1024), 16, 0, 0);
        }
        __syncthreads();
#pragma unroll
        for (int kk = 0; kk < 2; ++kk) {
            f16x8 af[4], bfr[4];
#pragma unroll
            for (int i = 0; i < 4; ++i)
                af[i] = *(const f16x8*)&As[(wr * 64 + i * 16 + (lane & 15)) * 64 + kk * 32 + (lane >> 4) * 8];
#pragma unroll
            for (int j = 0; j < 4; ++j)
                bfr[j] = *(const f16x8*)&Bs[(wc * 64 + j * 16 + (lane & 15)) * 64 + kk * 32 + (lane >> 4) * 8];
#pragma unroll
            for (int i = 0; i < 4; ++i)
#pragma unroll
                for (int j = 0; j < 4; ++j)
                    acc[i][j] = __builtin_amdgcn_mfma_f32_16x16x32_f16(af[i], bfr[j], acc[i][j], 0, 0, 0);
        }
        __syncthreads();
    }
}

// ---------------------------------------------------------------------------
// K4: d_out = O @ WoutT^T + bias.  grid (8,4), block 256. K=1024.
// ---------------------------------------------------------------------------
__global__ __launch_bounds__(256) void gemm_out(
    const f16* __restrict__ A, const f16* __restrict__ Bt,
    const float* __restrict__ bias, float* __restrict__ Cout)
{
    __shared__ f16 As[128 * 64];
    __shared__ f16 Bs[128 * 64];
    const int tn0 = blockIdx.x * 128;
    const int tm0 = blockIdx.y * 128;
    f32x4 acc[4][4];
#pragma unroll
    for (int i = 0; i < 4; ++i)
#pragma unroll
        for (int j = 0; j < 4; ++j) acc[i][j] = f32x4{0.f, 0.f, 0.f, 0.f};

    gemm_body(A + (size_t)tm0 * 1024, Bt + (size_t)tn0 * 1024,
              1024, 1024, 1024, As, Bs, acc, threadIdx.x);

    const int lane = threadIdx.x & 63, w = threadIdx.x >> 6;
    const int wr = w >> 1, wc = w & 1;
    const int cl = lane & 15, rg = lane >> 4;
#pragma unroll
    for (int i = 0; i < 4; ++i)
#pragma unroll
        for (int j = 0; j < 4; ++j) {
            const int cc = tn0 + wc * 64 + j * 16 + cl;
            const float bv = bias[cc];
#pragma unroll
            for (int q = 0; q < 4; ++q) {
                const int rr = tm0 + wr * 64 + i * 16 + rg * 4 + q;
                Cout[(size_t)rr * 1024 + cc] = acc[i][j][q] + bv;
            }
        }
}

// ---------------------------------------------------------------------------
// Per (b,h): dots = U_h * Wk_h^T, vv = W2_h * Wv2_h^T  (64x64, K=1024),
// softmax(dots*0.125), out = attn @ vv -> O (f16)
// grid: (16 heads, 8 batches), block 512 (8 waves)
// ---------------------------------------------------------------------------
__global__ __launch_bounds__(512) void attn_small(
    const f16* __restrict__ UW2, const f16* __restrict__ WqkvT,
    f16* __restrict__ O)
{
    __shared__ float dots[64][66];
    __shared__ float vv[64][66];
    const int h = blockIdx.x, b = blockIdx.y;
    const int tid = threadIdx.x, lane = tid & 63, w = tid >> 6;
    const int isVV = w >> 2;
    const int kq = w & 3;

    const f16* Arows = UW2 + (size_t)b * (2048 * 1024)
                           + (size_t)isVV * (1024 * 1024) + (size_t)h * 64 * 1024;
    const f16* Brows = WqkvT + (size_t)(isVV ? 3072 : 1024) * 1024 + (size_t)h * 64 * 1024;

    f32x4 acc[4][4];
#pragma unroll
    for (int i = 0; i < 4; ++i)
#pragma unroll
        for (int j = 0; j < 4; ++j) acc[i][j] = f32x4{0.f, 0.f, 0.f, 0.f};

    const int cl = lane & 15, kg = lane >> 4;
    for (int ks = 0; ks < 8; ++ks) {
        const int k0 = kq * 256 + ks * 32 + kg * 8;
        f16x8 af[4], bfr[4];
#pragma unroll
        for (int i = 0; i < 4; ++i)
            af[i] = *(const f16x8*)(Arows + (size_t)(i * 16 + cl) * 1024 + k0);
#pragma unroll
        for (int j = 0; j < 4; ++j)
            bfr[j] = *(const f16x8*)(Brows + (size_t)(j * 16 + cl) * 1024 + k0);
#pragma unroll
        for (int i = 0; i < 4; ++i)
#pragma unroll
            for (int j = 0; j < 4; ++j)
                acc[i][j] = __builtin_amdgcn_mfma_f32_16x16x32_f16(af[i], bfr[j], acc[i][j], 0, 0, 0);
    }

    float (*dst)[66] = isVV ? vv : dots;
#pragma unroll
    for (int r = 0; r < 4; ++r) {
        if (kq == r) {
            if (r == 0) {
#pragma unroll
                for (int i = 0; i < 4; ++i)
#pragma unroll
                    for (int j = 0; j < 4; ++j)
#pragma unroll
                        for (int q = 0; q < 4; ++q)
                            dst[i * 16 + kg * 4 + q][j * 16 + cl] = acc[i][j][q];
            } else {
#pragma unroll
                for (int i = 0; i < 4; ++i)
#pragma unroll
                    for (int j = 0; j < 4; ++j)
#pragma unroll
                        for (int q = 0; q < 4; ++q)
                            dst[i * 16 + kg * 4 + q][j * 16 + cl] += acc[i][j][q];
            }
        }
        __syncthreads();
    }

    if (tid < 64) {
        const int r = tid;
        float mx = -1e30f;
        for (int e = 0; e < 64; ++e) {
            const float v = dots[r][e] * 0.125f;
            dots[r][e] = v;
            mx = fmaxf(mx, v);
        }
        float s = 0.f;
        for (int e = 0; e < 64; ++e) {
            const float v = __expf(dots[r][e] - mx);
            dots[r][e] = v;
            s += v;
        }
        const float inv = 1.f / s;
        for (int e = 0; e < 64; ++e) dots[r][e] *= inv;
    }
    __syncthreads();

    {
        const int r = tid >> 3, f0 = (tid & 7) * 8;
        float o[8];
#pragma unroll
        for (int i = 0; i < 8; ++i) o[i] = 0.f;
        for (int e = 0; e < 64; ++e) {
            const float a = dots[r][e];
#pragma unroll
            for (int i = 0; i < 8; ++i) o[i] += a * vv[e][f0 + i];
        }
        f16* Od = O + (size_t)b * 64 * 1024 + (size_t)r * 1024 + h * 64 + f0;
#pragma unroll
        for (int i = 0; i < 8; ++i) Od[i] = (f16)o[i];
    }
}

// ---------------------------------------------------------------------------
extern "C" void kernel_launch(void* const* d_in, const int* in_sizes, int n_in,
                              void* d_out, int out_size, void* d_ws, size_t ws_size,
                              hipStream_t stream)
{
    const float* x    = (const float*)d_in[0];  // [8][4096][1024]
    const float* Wqkv = (const float*)d_in[1];  // [1024][4096]
    const float* Wout = (const float*)d_in[2];  // [1024][1024]
    const float* bout = (const float*)d_in[3];  // [1024]

    char* ws = (char*)d_ws;
    f16* xT    = (f16*)(ws + 0);           // [8][1024][4096]   67108864 B
    f16* WqkvT = (f16*)(ws + 67108864);    // [4096][1024]       8388608 B
    f16* WoutT = (f16*)(ws + 75497472);    // [1024][1024]       2097152 B
    f16* G     = (f16*)(ws + 77594624);    // [8][1024][1024]   16777216 B
    f16* Gp    = (f16*)(ws + 94371840);    // [2][8][1024][1024] 33554432 B
    f16* UW2   = (f16*)(ws + 94371840);    // union w/ Gp (qv runs after reduce)
    f16* O     = (f16*)(ws + 127926272);   // [8][64][1024]      1048576 B

    tr_cvt_kernel<<<dim3(16, 64, 8), 256, 0, stream>>>(x, xT, 4096, 1024);
    tr_cvt_kernel<<<dim3(64, 16, 1), 256, 0, stream>>>(Wqkv, WqkvT, 1024, 4096);
    tr_cvt_kernel<<<dim3(16, 16, 1), 256, 0, stream>>>(Wout, WoutT, 1024, 1024);

    // K1: full-G split-K=2, 256^2 tiles, counted-vmcnt pipelined (r5 core)
    gemm_syk256<<<256, 512, 0, stream>>>(xT, Gp);
    // G = Gp0 + Gp1
    reduce_sum<<<4096, 256, 0, stream>>>(Gp, G);
    // K2 fused: UW2 = [Wq^T G ; Wv^T G]
    gemm_qv256<<<256, 512, 0, stream>>>(WqkvT, G, UW2);
    // K3: per (b,h) small attention
    attn_small<<<dim3(16, 8), 512, 0, stream>>>(UW2, WqkvT, O);
    // K4: out = O @ WoutT^T + bias (single kernel, no atomics)
    gemm_out<<<dim3(8, 4), 256, 0, stream>>>(O, WoutT, bout, (float*)d_out);
}